// Round 4
// baseline (615.786 us; speedup 1.0000x reference)
//
#include <hip/hip_runtime.h>

#define FIN 128
#define H1_ 50
#define H2_ 10

#define BKT_SHIFT 7
#define BKT_W 128              // nodes per fine bucket
#define NB_MAX 800             // >= ceil(100000/128) = 782
#define SB_SHIFT 11
#define SB_W 2048              // nodes per super-bucket (= 16 fine buckets)
#define NSB_MAX 64             // >= ceil(100000/2048) = 49
#define SB_CAP 81920           // fixed segment capacity (1.25x expected 65536)
#define P1_CHUNK 8192          // edges per block, SB partition
#define P1F_CHUNK 4096         // edges per block, fine partition

typedef float f32x2 __attribute__((ext_vector_type(2)));
typedef float f32x4 __attribute__((ext_vector_type(4)));

// ---------------- bf16 helpers (RNE) ----------------

__device__ inline float bf2f(unsigned int u16) {
    union { unsigned int i; float f; } c; c.i = u16 << 16; return c.f;
}
__device__ inline unsigned short f2bf(float f) {
    union { float f; unsigned int i; } c; c.f = f;
    unsigned int x = c.i;
    return (unsigned short)((x + 0x7FFFu + ((x >> 16) & 1u)) >> 16);
}
__device__ inline void unpack8(uint4 v, float* f) {
    f[0] = bf2f(v.x & 0xFFFFu); f[1] = bf2f(v.x >> 16);
    f[2] = bf2f(v.y & 0xFFFFu); f[3] = bf2f(v.y >> 16);
    f[4] = bf2f(v.z & 0xFFFFu); f[5] = bf2f(v.z >> 16);
    f[6] = bf2f(v.w & 0xFFFFu); f[7] = bf2f(v.w >> 16);
}
__device__ inline void nt_store2(float* p, float a, float b) {
    f32x2 v; v.x = a; v.y = b;
    __builtin_nontemporal_store(v, (f32x2*)p);
}
__device__ inline void nt_store4(float* p, float a, float b, float c, float d) {
    f32x4 v; v.x = a; v.y = b; v.z = c; v.w = d;
    __builtin_nontemporal_store(v, (f32x4*)p);
}

// ======== level 1 (fused): SB partition + fine histogram in one pass ========

__global__ __launch_bounds__(256) void partition_sb(const int* __restrict__ src,
                                                    const int* __restrict__ dst,
                                                    int* __restrict__ sbcnt,
                                                    int* __restrict__ bcnt,
                                                    int* __restrict__ pairbuf1,
                                                    int E, int nsb) {
    __shared__ int lh[NB_MAX];     // fine histogram
    __shared__ int lhs[NSB_MAX];   // SB local cursor
    __shared__ int lbs[NSB_MAX];   // SB reserved global base
    int tid = threadIdx.x;
    for (int i = tid; i < NB_MAX; i += 256) lh[i] = 0;
    if (tid < NSB_MAX) lhs[tid] = 0;
    __syncthreads();
    int lo = blockIdx.x * P1_CHUNK;
    int hi = min(lo + P1_CHUNK, E);
    for (int e = lo + tid; e < hi; e += 256)
        atomicAdd(&lh[dst[e] >> BKT_SHIFT], 1);
    __syncthreads();
    if (tid < nsb) {
        int c = 0;
#pragma unroll
        for (int j = 0; j < 16; ++j) {
            int idx = tid * 16 + j;
            c += (idx < NB_MAX) ? lh[idx] : 0;
        }
        lbs[tid] = c ? (tid * SB_CAP + atomicAdd(&sbcnt[tid], c)) : 0;
    }
    for (int i = tid; i < NB_MAX; i += 256) {
        int c = lh[i];
        if (c) atomicAdd(&bcnt[i], c);
    }
    __syncthreads();
    for (int e = lo + tid; e < hi; e += 256) {
        int sv = src[e], d = dst[e];
        int b = d >> SB_SHIFT;
        int r = atomicAdd(&lhs[b], 1);
        pairbuf1[lbs[b] + r] = sv | ((d & (SB_W - 1)) << 17);
    }
}

// single block: scan fine counts -> bbase/bcursor
__global__ __launch_bounds__(256) void bucket_scan(const int* __restrict__ bcnt,
                                                   int* __restrict__ bbase,
                                                   int* __restrict__ bcursor,
                                                   int nb2, int E) {
    __shared__ int s[256];
    int t = threadIdx.x;
    int base = t * 4;
    int v0 = (base + 0 < nb2) ? bcnt[base + 0] : 0;
    int v1 = (base + 1 < nb2) ? bcnt[base + 1] : 0;
    int v2 = (base + 2 < nb2) ? bcnt[base + 2] : 0;
    int v3 = (base + 3 < nb2) ? bcnt[base + 3] : 0;
    int tsum = v0 + v1 + v2 + v3;
    s[t] = tsum;
    __syncthreads();
    for (int off = 1; off < 256; off <<= 1) {
        int x = (t >= off) ? s[t - off] : 0;
        __syncthreads();
        s[t] += x;
        __syncthreads();
    }
    int excl = s[t] - tsum;
    if (t == 0) bbase[nb2] = E;
    if (base + 0 < nb2) { bbase[base + 0] = excl; bcursor[base + 0] = excl; }
    excl += v0;
    if (base + 1 < nb2) { bbase[base + 1] = excl; bcursor[base + 1] = excl; }
    excl += v1;
    if (base + 2 < nb2) { bbase[base + 2] = excl; bcursor[base + 2] = excl; }
    excl += v2;
    if (base + 3 < nb2) { bbase[base + 3] = excl; bcursor[base + 3] = excl; }
}

// ======== level 2: partition each SB segment into its 16 fine buckets ======

__global__ __launch_bounds__(256) void partition_fine(const int* __restrict__ pairbuf1,
                                                      const int* __restrict__ sbcnt,
                                                      int* __restrict__ bcursor,
                                                      int* __restrict__ pairbuf2) {
    int sb = blockIdx.y;
    int cnt = sbcnt[sb];
    int rel = blockIdx.x * P1F_CHUNK;
    if (rel >= cnt) return;
    int lo = sb * SB_CAP + rel;
    int hi = sb * SB_CAP + min(rel + P1F_CHUNK, cnt);
    __shared__ int lh[16];
    __shared__ int lb[16];
    int tid = threadIdx.x;
    if (tid < 16) lh[tid] = 0;
    __syncthreads();
    for (int j = lo + tid; j < hi; j += 256)
        atomicAdd(&lh[(pairbuf1[j] >> 17) >> BKT_SHIFT], 1);
    __syncthreads();
    if (tid < 16) {
        int c = lh[tid];
        lb[tid] = c ? atomicAdd(&bcursor[sb * 16 + tid], c) : 0;
        lh[tid] = 0;
    }
    __syncthreads();
    for (int j = lo + tid; j < hi; j += 256) {
        int p = pairbuf1[j];
        int din = p >> 17;
        int fb = din >> BKT_SHIFT;
        int r = atomicAdd(&lh[fb], 1);
        pairbuf2[lb[fb] + r] = (p & 0x1FFFF) | ((din & (BKT_W - 1)) << 17);
    }
}

// ========== pass 2: per-bucket count + scan + rowptr/dinv + fill (fused) ==========

__global__ __launch_bounds__(256) void bucket_fill_scan(const int* __restrict__ pairbuf,
                                                        const int* __restrict__ bbase,
                                                        int* __restrict__ rowptr,
                                                        float* __restrict__ dinv,
                                                        int* __restrict__ ecol,
                                                        int N, int E) {
    __shared__ int cnt[BKT_W];
    __shared__ int sc[BKT_W];
    __shared__ int cur[BKT_W];
    int b = blockIdx.x;
    int base_node = b << BKT_SHIFT;
    int nnodes = min(BKT_W, N - base_node);
    int tid = threadIdx.x;
    if (tid < BKT_W) cnt[tid] = 0;
    __syncthreads();
    int lo = bbase[b], hi = bbase[b + 1];
    for (int j = lo + tid; j < hi; j += 256)
        atomicAdd(&cnt[pairbuf[j] >> 17], 1);
    __syncthreads();
    int c = (tid < BKT_W) ? cnt[tid] : 0;
    if (tid < BKT_W) sc[tid] = c;
    __syncthreads();
    for (int off = 1; off < BKT_W; off <<= 1) {
        int xv = (tid >= off && tid < BKT_W) ? sc[tid - off] : 0;
        __syncthreads();
        if (tid < BKT_W) sc[tid] += xv;
        __syncthreads();
    }
    if (tid < nnodes) {
        int rp = lo + sc[tid] - c;           // exclusive prefix within bucket
        rowptr[base_node + tid] = rp;
        cur[tid] = rp;
        dinv[base_node + tid] = rsqrtf(1.0f + (float)c);   // deg incl self-loop
    }
    __syncthreads();
    for (int j = lo + tid; j < hi; j += 256) {
        int p = pairbuf[j];
        int pos = atomicAdd(&cur[p >> 17], 1);
        ecol[pos] = p & 0x1FFFF;
    }
    if (b == (int)gridDim.x - 1 && tid == 0) rowptr[N] = E;
}

// ======== GEMM1 v5: writes feature-SLICED tables for L2-resident gathers ====
// slice s (s=0..2): bf16[N][16], features 16s..16s+15  (3.2 MB each < 4MB L2)
// mini:             bf16[N][2],  features 48..49        (400 KB)
// g=0..5 -> slice g>>1 half g&1; g=6 -> mini (o[0],o[1]); g=7 -> no store.

#define G1_NODES 128
#define SX_PITCH 132
#define KCHUNK 32
__global__ __launch_bounds__(256) void gemm1_kernel(const float* __restrict__ x,
                                                    const float* __restrict__ W1,
                                                    const float* __restrict__ dinv,
                                                    unsigned short* __restrict__ st1, int N) {
    __shared__ float sX[G1_NODES * SX_PITCH]; // 67.6 KB
    __shared__ float sW[KCHUNK * 64];         // 8 KB per k-chunk
    int tid = threadIdx.x;
    int nb = blockIdx.x * G1_NODES;
    {
        const float4* x4 = (const float4*)(x + (size_t)nb * FIN);
        for (int i = tid; i < G1_NODES * 32; i += 256) {   // 4096 float4 stages
            int ln = i >> 5, kk = i & 31;
            float4 v = (nb + ln < N) ? x4[(size_t)ln * 32 + kk]
                                     : make_float4(0.f, 0.f, 0.f, 0.f);
            *(float4*)(&sX[ln * SX_PITCH + kk * 4]) = v;
        }
    }
    int q = tid >> 3;         // 0..31
    int g = tid & 7;          // 0..7
    const float* xr0 = &sX[(4 * q + 0) * SX_PITCH];
    const float* xr1 = &sX[(4 * q + 1) * SX_PITCH];
    const float* xr2 = &sX[(4 * q + 2) * SX_PITCH];
    const float* xr3 = &sX[(4 * q + 3) * SX_PITCH];
    float acc[4][8];
#pragma unroll
    for (int i = 0; i < 4; ++i)
#pragma unroll
        for (int j = 0; j < 8; ++j) acc[i][j] = 0.0f;

    for (int kc = 0; kc < FIN / KCHUNK; ++kc) {
        __syncthreads();     // protect sW from previous iteration's readers
        for (int i = tid; i < KCHUNK * 64; i += 256) {
            int k = i >> 6, f = i & 63;
            sW[i] = (f < H1_) ? W1[(kc * KCHUNK + k) * H1_ + f] : 0.0f;
        }
        __syncthreads();
        int kb = kc * KCHUNK;
#pragma unroll 4
        for (int k = 0; k < KCHUNK; ++k) {
            float xv0 = xr0[kb + k];
            float xv1 = xr1[kb + k];
            float xv2 = xr2[kb + k];
            float xv3 = xr3[kb + k];
            const float* w = &sW[k * 64 + g * 8];
#pragma unroll
            for (int j = 0; j < 8; ++j) {
                float wv = w[j];
                acc[0][j] = fmaf(xv0, wv, acc[0][j]);
                acc[1][j] = fmaf(xv1, wv, acc[1][j]);
                acc[2][j] = fmaf(xv2, wv, acc[2][j]);
                acc[3][j] = fmaf(xv3, wv, acc[3][j]);
            }
        }
    }
#pragma unroll
    for (int i = 0; i < 4; ++i) {
        int node = nb + 4 * q + i;
        if (node >= N) continue;
        if (g == 7) continue;                       // features 56..63 never read
        float di = dinv[node];
        unsigned short o[8];
#pragma unroll
        for (int j = 0; j < 8; ++j) o[j] = f2bf(acc[i][j] * di);
        if (g < 6) {
            uint4 pk;
            pk.x = (unsigned)o[0] | ((unsigned)o[1] << 16);
            pk.y = (unsigned)o[2] | ((unsigned)o[3] << 16);
            pk.z = (unsigned)o[4] | ((unsigned)o[5] << 16);
            pk.w = (unsigned)o[6] | ((unsigned)o[7] << 16);
            *(uint4*)(st1 + (size_t)(g >> 1) * 16 * N + (size_t)node * 16 + (g & 1) * 8) = pk;
        } else {                                    // g==6: features 48,49 -> mini
            unsigned int pk = (unsigned)o[0] | ((unsigned)o[1] << 16);
            *(unsigned int*)(st1 + (size_t)48 * N + (size_t)node * 2) = pk;
        }
    }
}

// ==== aggregate layer 1, one 16-feature slice (table 3.2MB, L2-resident) ====
// 2 threads/dst: g in {0,1} covers features fb+8g..fb+8g+7. ecol NT-loaded,
// out NT-stored so streams don't evict the table from L2.

__global__ __launch_bounds__(256) void csr_agg1_slice(const unsigned short* __restrict__ tab,
                                                      const int* __restrict__ rowptr,
                                                      const int* __restrict__ ecol,
                                                      const float* __restrict__ dinv,
                                                      const float* __restrict__ b,   // b1+fb
                                                      float* __restrict__ out,       // out1+fb
                                                      int N) {
    int idx = blockIdx.x * blockDim.x + threadIdx.x;
    if (idx >= N * 2) return;
    int d = idx >> 1;
    int g = idx & 1;
    const unsigned short* row = tab + g * 8;
    float acc[8];
    {
        uint4 sv = *(const uint4*)(row + (size_t)d * 16);   // self-loop term
        float f[8]; unpack8(sv, f);
#pragma unroll
        for (int k = 0; k < 8; ++k) acc[k] = f[k];
    }
    int j = rowptr[d], end = rowptr[d + 1];
    for (; j + 3 < end; j += 4) {
        int s0 = __builtin_nontemporal_load(&ecol[j]);
        int s1 = __builtin_nontemporal_load(&ecol[j + 1]);
        int s2 = __builtin_nontemporal_load(&ecol[j + 2]);
        int s3 = __builtin_nontemporal_load(&ecol[j + 3]);
        uint4 v0 = *(const uint4*)(row + (size_t)s0 * 16);
        uint4 v1 = *(const uint4*)(row + (size_t)s1 * 16);
        uint4 v2 = *(const uint4*)(row + (size_t)s2 * 16);
        uint4 v3 = *(const uint4*)(row + (size_t)s3 * 16);
        float f0[8], f1[8], f2[8], f3[8];
        unpack8(v0, f0); unpack8(v1, f1); unpack8(v2, f2); unpack8(v3, f3);
#pragma unroll
        for (int k = 0; k < 8; ++k) acc[k] += (f0[k] + f1[k]) + (f2[k] + f3[k]);
    }
    for (; j < end; ++j) {
        int s = __builtin_nontemporal_load(&ecol[j]);
        uint4 v = *(const uint4*)(row + (size_t)s * 16);
        float f[8]; unpack8(v, f);
#pragma unroll
        for (int k = 0; k < 8; ++k) acc[k] += f[k];
    }
    float vd = dinv[d];
    float* op = out + (size_t)d * H1_ + 8 * g;    // fb folded into out/b
#pragma unroll
    for (int k = 0; k < 4; ++k) {
        float r0 = fmaxf(fmaf(vd, acc[2 * k],     b[8 * g + 2 * k]),     0.0f);
        float r1 = fmaxf(fmaf(vd, acc[2 * k + 1], b[8 * g + 2 * k + 1]), 0.0f);
        nt_store2(op + 2 * k, r0, r1);
    }
}

// ==== aggregate layer 1, features 48..49 (table 400KB, L2-resident) ====

__global__ __launch_bounds__(256) void csr_agg1_mini(const unsigned short* __restrict__ tab,
                                                     const int* __restrict__ rowptr,
                                                     const int* __restrict__ ecol,
                                                     const float* __restrict__ dinv,
                                                     const float* __restrict__ b,
                                                     float* __restrict__ out, int N) {
    int d = blockIdx.x * blockDim.x + threadIdx.x;
    if (d >= N) return;
    unsigned int sv = *(const unsigned int*)(tab + (size_t)d * 2);
    float acc0 = bf2f(sv & 0xFFFFu), acc1 = bf2f(sv >> 16);
    int j = rowptr[d], end = rowptr[d + 1];
    for (; j + 3 < end; j += 4) {
        int s0 = __builtin_nontemporal_load(&ecol[j]);
        int s1 = __builtin_nontemporal_load(&ecol[j + 1]);
        int s2 = __builtin_nontemporal_load(&ecol[j + 2]);
        int s3 = __builtin_nontemporal_load(&ecol[j + 3]);
        unsigned int v0 = *(const unsigned int*)(tab + (size_t)s0 * 2);
        unsigned int v1 = *(const unsigned int*)(tab + (size_t)s1 * 2);
        unsigned int v2 = *(const unsigned int*)(tab + (size_t)s2 * 2);
        unsigned int v3 = *(const unsigned int*)(tab + (size_t)s3 * 2);
        acc0 += (bf2f(v0 & 0xFFFFu) + bf2f(v1 & 0xFFFFu)) + (bf2f(v2 & 0xFFFFu) + bf2f(v3 & 0xFFFFu));
        acc1 += (bf2f(v0 >> 16) + bf2f(v1 >> 16)) + (bf2f(v2 >> 16) + bf2f(v3 >> 16));
    }
    for (; j < end; ++j) {
        int s = __builtin_nontemporal_load(&ecol[j]);
        unsigned int v = *(const unsigned int*)(tab + (size_t)s * 2);
        acc0 += bf2f(v & 0xFFFFu);
        acc1 += bf2f(v >> 16);
    }
    float vd = dinv[d];
    float r0 = fmaxf(fmaf(vd, acc0, b[48]), 0.0f);
    float r1 = fmaxf(fmaf(vd, acc1, b[49]), 0.0f);
    nt_store2(out + (size_t)d * H1_ + 48, r0, r1);
}

// ===== GEMM2: writes split tables st2a[N][8] (f0..7) and st2b[N][2] (f8..9) =====

__global__ __launch_bounds__(256) void gemm2_kernel(const float* __restrict__ h,
                                                    const float* __restrict__ W2,
                                                    const float* __restrict__ dinv,
                                                    float* __restrict__ st2a,
                                                    float* __restrict__ st2b, int n16) {
    __shared__ float sW[H1_ * H2_];   // 2 KB
    int tid = threadIdx.x;
    for (int i = tid; i < H1_ * H2_; i += 256) sW[i] = W2[i];
    __syncthreads();
    int idx = blockIdx.x * blockDim.x + tid;
    if (idx >= n16) return;
    int node = idx >> 4;
    int f    = idx & 15;
    if (f >= H2_) return;
    const float* hr = &h[(size_t)node * H1_];
    float acc = 0.0f;
#pragma unroll
    for (int k = 0; k < H1_; ++k) acc = fmaf(hr[k], sW[k * H2_ + f], acc);
    float v = acc * dinv[node];
    if (f < 8) st2a[(size_t)node * 8 + f] = v;
    else       st2b[(size_t)node * 2 + (f - 8)] = v;
}

// ==== aggregate layer 2 pass A: features 0..7 from st2a (3.2MB, L2-resident) ====
// 2 threads/dst, float4 each; writes z0[N][8].

__global__ __launch_bounds__(256) void csr_agg2_a(const float* __restrict__ st,
                                                  const int* __restrict__ rowptr,
                                                  const int* __restrict__ ecol,
                                                  const float* __restrict__ dinv,
                                                  const float* __restrict__ b,
                                                  float* __restrict__ z0, int N) {
    int idx = blockIdx.x * blockDim.x + threadIdx.x;
    if (idx >= N * 2) return;
    int d = idx >> 1;
    int g = idx & 1;
    const float* row = st + g * 4;
    float4 acc = *(const float4*)(row + (size_t)d * 8);   // self-loop term
    int j = rowptr[d], end = rowptr[d + 1];
    for (; j + 3 < end; j += 4) {
        int s0 = __builtin_nontemporal_load(&ecol[j]);
        int s1 = __builtin_nontemporal_load(&ecol[j + 1]);
        int s2 = __builtin_nontemporal_load(&ecol[j + 2]);
        int s3 = __builtin_nontemporal_load(&ecol[j + 3]);
        float4 a0 = *(const float4*)(row + (size_t)s0 * 8);
        float4 a1 = *(const float4*)(row + (size_t)s1 * 8);
        float4 a2 = *(const float4*)(row + (size_t)s2 * 8);
        float4 a3 = *(const float4*)(row + (size_t)s3 * 8);
        acc.x += (a0.x + a1.x) + (a2.x + a3.x);
        acc.y += (a0.y + a1.y) + (a2.y + a3.y);
        acc.z += (a0.z + a1.z) + (a2.z + a3.z);
        acc.w += (a0.w + a1.w) + (a2.w + a3.w);
    }
    for (; j < end; ++j) {
        int s = __builtin_nontemporal_load(&ecol[j]);
        float4 a = *(const float4*)(row + (size_t)s * 8);
        acc.x += a.x; acc.y += a.y; acc.z += a.z; acc.w += a.w;
    }
    float vd = dinv[d];
    nt_store4(z0 + (size_t)d * 8 + 4 * g,
              fmaf(vd, acc.x, b[4 * g + 0]),
              fmaf(vd, acc.y, b[4 * g + 1]),
              fmaf(vd, acc.z, b[4 * g + 2]),
              fmaf(vd, acc.w, b[4 * g + 3]));
}

// ==== aggregate layer 2 pass B: features 8..9 from st2b (800KB, L2-resident) ====

__global__ __launch_bounds__(256) void csr_agg2_b(const float* __restrict__ st,
                                                  const int* __restrict__ rowptr,
                                                  const int* __restrict__ ecol,
                                                  const float* __restrict__ dinv,
                                                  const float* __restrict__ b,
                                                  float* __restrict__ z1, int N) {
    int d = blockIdx.x * blockDim.x + threadIdx.x;
    if (d >= N) return;
    float2 acc = *(const float2*)(st + (size_t)d * 2);   // self-loop term
    int j = rowptr[d], end = rowptr[d + 1];
    for (; j + 3 < end; j += 4) {
        int s0 = __builtin_nontemporal_load(&ecol[j]);
        int s1 = __builtin_nontemporal_load(&ecol[j + 1]);
        int s2 = __builtin_nontemporal_load(&ecol[j + 2]);
        int s3 = __builtin_nontemporal_load(&ecol[j + 3]);
        float2 a0 = *(const float2*)(st + (size_t)s0 * 2);
        float2 a1 = *(const float2*)(st + (size_t)s1 * 2);
        float2 a2 = *(const float2*)(st + (size_t)s2 * 2);
        float2 a3 = *(const float2*)(st + (size_t)s3 * 2);
        acc.x += (a0.x + a1.x) + (a2.x + a3.x);
        acc.y += (a0.y + a1.y) + (a2.y + a3.y);
    }
    for (; j < end; ++j) {
        int s = __builtin_nontemporal_load(&ecol[j]);
        float2 a = *(const float2*)(st + (size_t)s * 2);
        acc.x += a.x; acc.y += a.y;
    }
    float vd = dinv[d];
    nt_store2(z1 + (size_t)d * 2, fmaf(vd, acc.x, b[8]), fmaf(vd, acc.y, b[9]));
}

// ================= decode: split-z gathers, 2 distinct lines per edge =======

__global__ __launch_bounds__(256) void decode_kernel(const float* __restrict__ z0,
                                                     const float* __restrict__ z1,
                                                     const int* __restrict__ pos,
                                                     const int* __restrict__ neg,
                                                     float* __restrict__ logits, int EP) {
    int i = blockIdx.x * blockDim.x + threadIdx.x;
    if (i >= 2 * EP) return;
    int a, b;
    if (i < EP) {
        a = __builtin_nontemporal_load(&pos[i]);
        b = __builtin_nontemporal_load(&pos[EP + i]);
    } else {
        int j = i - EP;
        a = __builtin_nontemporal_load(&neg[j]);
        b = __builtin_nontemporal_load(&neg[EP + j]);
    }
    const float4* za = (const float4*)(z0 + (size_t)a * 8);
    const float4* zb = (const float4*)(z0 + (size_t)b * 8);
    float4 a0 = za[0];
    float4 a1 = za[1];
    float4 b0 = zb[0];
    float4 b1 = zb[1];
    float2 a2 = *(const float2*)(z1 + (size_t)a * 2);
    float2 b2 = *(const float2*)(z1 + (size_t)b * 2);
    float acc = a0.x * b0.x;
    acc = fmaf(a0.y, b0.y, acc);
    acc = fmaf(a0.z, b0.z, acc);
    acc = fmaf(a0.w, b0.w, acc);
    acc = fmaf(a1.x, b1.x, acc);
    acc = fmaf(a1.y, b1.y, acc);
    acc = fmaf(a1.z, b1.z, acc);
    acc = fmaf(a1.w, b1.w, acc);
    acc = fmaf(a2.x, b2.x, acc);
    acc = fmaf(a2.y, b2.y, acc);
    __builtin_nontemporal_store(acc, &logits[i]);
}

// ================= launch =================

extern "C" void kernel_launch(void* const* d_in, const int* in_sizes, int n_in,
                              void* d_out, int out_size, void* d_ws, size_t ws_size,
                              hipStream_t stream) {
    const float* x   = (const float*)d_in[0];
    const float* W1  = (const float*)d_in[1];
    const float* b1  = (const float*)d_in[2];
    const float* W2  = (const float*)d_in[3];
    const float* b2  = (const float*)d_in[4];
    const int* train = (const int*)d_in[5];
    const int* pos   = (const int*)d_in[6];
    const int* neg   = (const int*)d_in[7];

    const int N  = in_sizes[0] / FIN;       // 100000
    const int E  = in_sizes[5] / 2;         // 3200000
    const int EP = in_sizes[6] / 2;         // 1600000

    const int* tsrc = train;
    const int* tdst = train + E;

    // ---- workspace layout (~34 MB peak) ----
    // ints: rowptr[N+1] | bcnt[NB_MAX] | sbcnt[NSB_MAX] | bbase[NB_MAX+1] | bcursor[NB_MAX]
    // floats: dinv[N]
    // regA = 32N floats (12.8MB), sequential overlays:
    //   phase CSR : pairbuf2 int[E=32N]                     (32N f)
    //   phase L1  : st1 slices bf16: 3x N*16 + N*2 = 50N us (25N f)
    //   phase L2  : st2a[8N f] | st2b[2N f] | z0[8N f] | z1[2N f]  (20N f)
    // regB = 50N floats (20MB): pairbuf1 int[49*SB_CAP] -> out1[50N]
    size_t off = 0;
    int* rowptr   = (int*)d_ws;              off += (size_t)N + 1;
    int* bcnt     = (int*)d_ws + off;        off += NB_MAX;
    int* sbcnt    = (int*)d_ws + off;        off += NSB_MAX;
    int* bbase    = (int*)d_ws + off;        off += NB_MAX + 1;
    int* bcursor  = (int*)d_ws + off;        off += NB_MAX;
    float* dinv   = (float*)d_ws + off;      off += N;
    off = (off + 15) & ~(size_t)15;          // 64B-align regA
    float* regA   = (float*)d_ws + off;      off += (size_t)32 * N;
    float* regB   = (float*)d_ws + off;
    int* pairbuf2 = (int*)regA;                      // E ints, dead after fill
    unsigned short* st1 = (unsigned short*)regA;     // 50N ushorts (3 slices + mini)
    float* st2a   = regA;                            // 8N floats, after agg1
    float* st2b   = regA + (size_t)8 * N;            // 2N floats
    float* z0     = regA + (size_t)10 * N;           // 8N floats (32B rows)
    float* z1     = regA + (size_t)18 * N;           // 2N floats (8B rows)
    int* pairbuf1 = (int*)regB;                      // 49*SB_CAP ints, dead after fine
    float* out1   = regB;                            // h after relu, 50N floats
    int* ecol     = (int*)d_out;                     // E ints; dead before decode
    float* logits = (float*)d_out;

    const int NB2 = (N + BKT_W - 1) >> BKT_SHIFT;   // 782 <= NB_MAX
    const int NSB = (N + SB_W - 1) >> SB_SHIFT;     // 49 <= NSB_MAX
    const int P1B = (E + P1_CHUNK - 1) / P1_CHUNK;  // 391
    const int P1FB = (SB_CAP + P1F_CHUNK - 1) / P1F_CHUNK;   // 20

    // ---- CSR build (fused count+partition, fixed-capacity SB segments) ----
    hipMemsetAsync(bcnt, 0, (NB_MAX + NSB_MAX) * sizeof(int), stream);  // bcnt + sbcnt
    partition_sb<<<P1B, 256, 0, stream>>>(tsrc, tdst, sbcnt, bcnt, pairbuf1, E, NSB);
    bucket_scan<<<1, 256, 0, stream>>>(bcnt, bbase, bcursor, NB2, E);
    partition_fine<<<dim3(P1FB, NSB), 256, 0, stream>>>(pairbuf1, sbcnt, bcursor, pairbuf2);
    bucket_fill_scan<<<NB2, 256, 0, stream>>>(pairbuf2, bbase, rowptr, dinv, ecol, N, E);

    // ---- layer 1 ----
    gemm1_kernel<<<(N + G1_NODES - 1) / G1_NODES, 256, 0, stream>>>(x, W1, dinv, st1, N);
    for (int s = 0; s < 3; ++s)
        csr_agg1_slice<<<(N * 2 + 255) / 256, 256, 0, stream>>>(
            st1 + (size_t)s * 16 * N, rowptr, ecol, dinv, b1 + 16 * s, out1 + 16 * s, N);
    csr_agg1_mini<<<(N + 255) / 256, 256, 0, stream>>>(
        st1 + (size_t)48 * N, rowptr, ecol, dinv, b1, out1, N);

    // ---- layer 2 ----
    gemm2_kernel<<<(N * 16 + 255) / 256, 256, 0, stream>>>(out1, W2, dinv, st2a, st2b, N * 16);
    csr_agg2_a<<<(N * 2 + 255) / 256, 256, 0, stream>>>(st2a, rowptr, ecol, dinv, b2, z0, N);
    csr_agg2_b<<<(N + 255) / 256, 256, 0, stream>>>(st2b, rowptr, ecol, dinv, b2, z1, N);

    // ---- decode ----
    decode_kernel<<<(2 * EP + 255) / 256, 256, 0, stream>>>(z0, z1, pos, neg, logits, EP);
}

// Round 5
// 457.818 us; speedup vs baseline: 1.3450x; 1.3450x over previous
//
#include <hip/hip_runtime.h>

#define FIN 128
#define H1_ 50
#define H2_ 10
#define ST2S 16                // st2 padded row stride (64B-aligned rows)

#define BKT_SHIFT 7
#define BKT_W 128              // nodes per fine bucket
#define NB_MAX 800             // >= ceil(100000/128) = 782
#define SB_SHIFT 11
#define SB_W 2048              // nodes per super-bucket (= 16 fine buckets)
#define NSB_MAX 64             // >= ceil(100000/2048) = 49
#define SB_CAP 81920           // fixed segment capacity (1.25x expected 65536)
#define P1_CHUNK 8192          // edges per block, SB partition
#define P1F_CHUNK 4096         // edges per block, fine partition
#define SCH 16                 // src chunks for L2-locality sort (src>>13 -> 0..12)

// ---------------- bf16 helpers (RNE) ----------------

__device__ inline float bf2f(unsigned int u16) {
    union { unsigned int i; float f; } c; c.i = u16 << 16; return c.f;
}
__device__ inline unsigned short f2bf(float f) {
    union { float f; unsigned int i; } c; c.f = f;
    unsigned int x = c.i;
    return (unsigned short)((x + 0x7FFFu + ((x >> 16) & 1u)) >> 16);
}

// ======== level 1 (fused): SB partition + fine histogram in one pass ========
// record: src (bits 0..16) | dst-within-SB (bits 17..27)

__global__ __launch_bounds__(256) void partition_sb(const int* __restrict__ src,
                                                    const int* __restrict__ dst,
                                                    int* __restrict__ sbcnt,
                                                    int* __restrict__ bcnt,
                                                    int* __restrict__ pairbuf1,
                                                    int E, int nsb) {
    __shared__ int lh[NB_MAX];     // fine histogram
    __shared__ int lhs[NSB_MAX];   // SB local cursor
    __shared__ int lbs[NSB_MAX];   // SB reserved global base
    int tid = threadIdx.x;
    for (int i = tid; i < NB_MAX; i += 256) lh[i] = 0;
    if (tid < NSB_MAX) lhs[tid] = 0;
    __syncthreads();
    int lo = blockIdx.x * P1_CHUNK;
    int hi = min(lo + P1_CHUNK, E);
    for (int e = lo + tid; e < hi; e += 256)
        atomicAdd(&lh[dst[e] >> BKT_SHIFT], 1);
    __syncthreads();
    if (tid < nsb) {
        int c = 0;
#pragma unroll
        for (int j = 0; j < 16; ++j) {
            int idx = tid * 16 + j;
            c += (idx < NB_MAX) ? lh[idx] : 0;
        }
        lbs[tid] = c ? (tid * SB_CAP + atomicAdd(&sbcnt[tid], c)) : 0;
    }
    for (int i = tid; i < NB_MAX; i += 256) {
        int c = lh[i];
        if (c) atomicAdd(&bcnt[i], c);
    }
    __syncthreads();
    for (int e = lo + tid; e < hi; e += 256) {
        int sv = src[e], d = dst[e];
        int b = d >> SB_SHIFT;
        int r = atomicAdd(&lhs[b], 1);
        pairbuf1[lbs[b] + r] = sv | ((d & (SB_W - 1)) << 17);
    }
}

// single block: scan fine counts -> bbase
__global__ __launch_bounds__(256) void bucket_scan(const int* __restrict__ bcnt,
                                                   int* __restrict__ bbase,
                                                   int* __restrict__ bcursor,
                                                   int nb2, int E) {
    __shared__ int s[256];
    int t = threadIdx.x;
    int base = t * 4;
    int v0 = (base + 0 < nb2) ? bcnt[base + 0] : 0;
    int v1 = (base + 1 < nb2) ? bcnt[base + 1] : 0;
    int v2 = (base + 2 < nb2) ? bcnt[base + 2] : 0;
    int v3 = (base + 3 < nb2) ? bcnt[base + 3] : 0;
    int tsum = v0 + v1 + v2 + v3;
    s[t] = tsum;
    __syncthreads();
    for (int off = 1; off < 256; off <<= 1) {
        int x = (t >= off) ? s[t - off] : 0;
        __syncthreads();
        s[t] += x;
        __syncthreads();
    }
    int excl = s[t] - tsum;
    if (t == 0) bbase[nb2] = E;
    if (base + 0 < nb2) { bbase[base + 0] = excl; bcursor[base + 0] = excl; }
    excl += v0;
    if (base + 1 < nb2) { bbase[base + 1] = excl; bcursor[base + 1] = excl; }
    excl += v1;
    if (base + 2 < nb2) { bbase[base + 2] = excl; bcursor[base + 2] = excl; }
    excl += v2;
    if (base + 3 < nb2) { bbase[base + 3] = excl; bcursor[base + 3] = excl; }
}

// ======== level 2: partition each SB segment into its 16 fine buckets ======

__global__ __launch_bounds__(256) void partition_fine(const int* __restrict__ pairbuf1,
                                                      const int* __restrict__ sbcnt,
                                                      int* __restrict__ bcursor,
                                                      int* __restrict__ pairbuf2) {
    int sb = blockIdx.y;
    int cnt = sbcnt[sb];
    int rel = blockIdx.x * P1F_CHUNK;
    if (rel >= cnt) return;
    int lo = sb * SB_CAP + rel;
    int hi = sb * SB_CAP + min(rel + P1F_CHUNK, cnt);
    __shared__ int lh[16];
    __shared__ int lb[16];
    int tid = threadIdx.x;
    if (tid < 16) lh[tid] = 0;
    __syncthreads();
    for (int j = lo + tid; j < hi; j += 256)
        atomicAdd(&lh[(pairbuf1[j] >> 17) >> BKT_SHIFT], 1);
    __syncthreads();
    if (tid < 16) {
        int c = lh[tid];
        lb[tid] = c ? atomicAdd(&bcursor[sb * 16 + tid], c) : 0;
        lh[tid] = 0;
    }
    __syncthreads();
    for (int j = lo + tid; j < hi; j += 256) {
        int p = pairbuf1[j];
        int din = p >> 17;
        int fb = din >> BKT_SHIFT;
        int r = atomicAdd(&lh[fb], 1);
        pairbuf2[lb[fb] + r] = (p & 0x1FFFF) | ((din & (BKT_W - 1)) << 17);
    }
}

// ========== pass 2: per-bucket count + scan + rowptr/dinv + fill, now with
// per-(node, src-chunk) ordering: each dst's edge list is grouped by src>>13
// (16 chunks of <=8192 nodes = ~1MB of st1p each). Aggregation kernels are
// unchanged; the chunked order gives them L2 temporal locality on gathers. ==

__global__ __launch_bounds__(256) void bucket_fill_scan(const int* __restrict__ pairbuf,
                                                        const int* __restrict__ bbase,
                                                        int* __restrict__ rowptr,
                                                        float* __restrict__ dinv,
                                                        int* __restrict__ ecol,
                                                        int N, int E) {
    __shared__ int cnt2[BKT_W * SCH];   // 8KB: per-(node,chunk) count -> cursor
    __shared__ int sc[BKT_W];
    int b = blockIdx.x;
    int base_node = b << BKT_SHIFT;
    int nnodes = min(BKT_W, N - base_node);
    int tid = threadIdx.x;
    for (int i = tid; i < BKT_W * SCH; i += 256) cnt2[i] = 0;
    __syncthreads();
    int lo = bbase[b], hi = bbase[b + 1];
    for (int j = lo + tid; j < hi; j += 256) {
        int p = pairbuf[j];
        atomicAdd(&cnt2[(p >> 17) * SCH + ((p & 0x1FFFF) >> 13)], 1);
    }
    __syncthreads();
    int tsum = 0;
    if (tid < BKT_W) {
#pragma unroll
        for (int c = 0; c < SCH; ++c) tsum += cnt2[tid * SCH + c];
        sc[tid] = tsum;
    }
    __syncthreads();
    for (int off = 1; off < BKT_W; off <<= 1) {
        int xv = (tid >= off && tid < BKT_W) ? sc[tid - off] : 0;
        __syncthreads();
        if (tid < BKT_W) sc[tid] += xv;
        __syncthreads();
    }
    if (tid < nnodes) {
        int rp = lo + sc[tid] - tsum;        // exclusive prefix within bucket
        rowptr[base_node + tid] = rp;
        dinv[base_node + tid] = rsqrtf(1.0f + (float)tsum);   // deg incl self-loop
        int run = rp;                        // convert counts -> chunk cursors
#pragma unroll
        for (int c = 0; c < SCH; ++c) {
            int v = cnt2[tid * SCH + c];
            cnt2[tid * SCH + c] = run;
            run += v;
        }
    }
    __syncthreads();
    for (int j = lo + tid; j < hi; j += 256) {
        int p = pairbuf[j];
        int s = p & 0x1FFFF;
        int pos = atomicAdd(&cnt2[(p >> 17) * SCH + (s >> 13)], 1);
        ecol[pos] = s;
    }
    if (b == (int)gridDim.x - 1 && tid == 0) rowptr[N] = E;
}

// ======== GEMM1 v4: 4-node x 8-feat thread tile, monolithic st1p[N][64] ====

#define G1_NODES 128
#define SX_PITCH 132
#define KCHUNK 32
__global__ __launch_bounds__(256) void gemm1_kernel(const float* __restrict__ x,
                                                    const float* __restrict__ W1,
                                                    const float* __restrict__ dinv,
                                                    unsigned short* __restrict__ st1p, int N) {
    __shared__ float sX[G1_NODES * SX_PITCH]; // 67.6 KB
    __shared__ float sW[KCHUNK * 64];         // 8 KB per k-chunk
    int tid = threadIdx.x;
    int nb = blockIdx.x * G1_NODES;
    {
        const float4* x4 = (const float4*)(x + (size_t)nb * FIN);
        for (int i = tid; i < G1_NODES * 32; i += 256) {   // 4096 float4 stages
            int ln = i >> 5, kk = i & 31;
            float4 v = (nb + ln < N) ? x4[(size_t)ln * 32 + kk]
                                     : make_float4(0.f, 0.f, 0.f, 0.f);
            *(float4*)(&sX[ln * SX_PITCH + kk * 4]) = v;
        }
    }
    int q = tid >> 3;         // 0..31
    int g = tid & 7;          // 0..7
    const float* xr0 = &sX[(4 * q + 0) * SX_PITCH];
    const float* xr1 = &sX[(4 * q + 1) * SX_PITCH];
    const float* xr2 = &sX[(4 * q + 2) * SX_PITCH];
    const float* xr3 = &sX[(4 * q + 3) * SX_PITCH];
    float acc[4][8];
#pragma unroll
    for (int i = 0; i < 4; ++i)
#pragma unroll
        for (int j = 0; j < 8; ++j) acc[i][j] = 0.0f;

    for (int kc = 0; kc < FIN / KCHUNK; ++kc) {
        __syncthreads();     // protect sW from previous iteration's readers
        for (int i = tid; i < KCHUNK * 64; i += 256) {
            int k = i >> 6, f = i & 63;
            sW[i] = (f < H1_) ? W1[(kc * KCHUNK + k) * H1_ + f] : 0.0f;
        }
        __syncthreads();
        int kb = kc * KCHUNK;
#pragma unroll 4
        for (int k = 0; k < KCHUNK; ++k) {
            float xv0 = xr0[kb + k];
            float xv1 = xr1[kb + k];
            float xv2 = xr2[kb + k];
            float xv3 = xr3[kb + k];
            const float* w = &sW[k * 64 + g * 8];
#pragma unroll
            for (int j = 0; j < 8; ++j) {
                float wv = w[j];
                acc[0][j] = fmaf(xv0, wv, acc[0][j]);
                acc[1][j] = fmaf(xv1, wv, acc[1][j]);
                acc[2][j] = fmaf(xv2, wv, acc[2][j]);
                acc[3][j] = fmaf(xv3, wv, acc[3][j]);
            }
        }
    }
#pragma unroll
    for (int i = 0; i < 4; ++i) {
        int node = nb + 4 * q + i;
        if (node >= N) continue;
        if (g == 7) continue;             // shorts 56..63 never read by agg1
        float di = dinv[node];
        unsigned short o[8];
#pragma unroll
        for (int j = 0; j < 8; ++j) o[j] = f2bf(acc[i][j] * di);
        uint4 pk;
        pk.x = (unsigned)o[0] | ((unsigned)o[1] << 16);
        pk.y = (unsigned)o[2] | ((unsigned)o[3] << 16);
        pk.z = (unsigned)o[4] | ((unsigned)o[5] << 16);
        pk.w = (unsigned)o[6] | ((unsigned)o[7] << 16);
        *(uint4*)(st1p + (size_t)node * 64 + g * 8) = pk;
    }
}

// ============ aggregate layer 1: bf16 gather, fp32 accumulate ============
// 25 threads/dst, 2 features each (round-2 form, best measured). Chunk-sorted
// ecol gives the random src gathers L2 temporal locality.

#define F2 25
__global__ __launch_bounds__(256) void csr_aggregate1(const unsigned short* __restrict__ st,
                                                      const int* __restrict__ rowptr,
                                                      const int* __restrict__ ecol,
                                                      const float* __restrict__ dinv,
                                                      const float* __restrict__ b,
                                                      float* __restrict__ out, int N) {
    int idx = blockIdx.x * blockDim.x + threadIdx.x;
    if (idx >= N * F2) return;
    int d  = idx / F2;
    int fp = idx - d * F2;
    int fo = 2 * fp;
    unsigned int self2 = *(const unsigned int*)(st + (size_t)d * 64 + fo);
    float acc0 = bf2f(self2 & 0xFFFFu);
    float acc1 = bf2f(self2 >> 16);
    int j = rowptr[d], end = rowptr[d + 1];
    for (; j + 3 < end; j += 4) {
        int s0 = ecol[j], s1 = ecol[j + 1], s2 = ecol[j + 2], s3 = ecol[j + 3];
        unsigned int v0 = *(const unsigned int*)(st + (size_t)s0 * 64 + fo);
        unsigned int v1 = *(const unsigned int*)(st + (size_t)s1 * 64 + fo);
        unsigned int v2 = *(const unsigned int*)(st + (size_t)s2 * 64 + fo);
        unsigned int v3 = *(const unsigned int*)(st + (size_t)s3 * 64 + fo);
        acc0 += (bf2f(v0 & 0xFFFFu) + bf2f(v1 & 0xFFFFu)) + (bf2f(v2 & 0xFFFFu) + bf2f(v3 & 0xFFFFu));
        acc1 += (bf2f(v0 >> 16) + bf2f(v1 >> 16)) + (bf2f(v2 >> 16) + bf2f(v3 >> 16));
    }
    for (; j < end; ++j) {
        unsigned int v = *(const unsigned int*)(st + (size_t)ecol[j] * 64 + fo);
        acc0 += bf2f(v & 0xFFFFu);
        acc1 += bf2f(v >> 16);
    }
    float vd = dinv[d];
    float r0 = fmaxf(fmaf(vd, acc0, b[fo]),     0.0f);
    float r1 = fmaxf(fmaf(vd, acc1, b[fo + 1]), 0.0f);
    *(float2*)(out + (size_t)d * H1_ + fo) = make_float2(r0, r1);
}

// ===== GEMM2: st2[node*16+f] = (h @ W2)[node,f] * dinv[node]; f in [10,16)=0 =====

__global__ __launch_bounds__(256) void gemm2_kernel(const float* __restrict__ h,
                                                    const float* __restrict__ W2,
                                                    const float* __restrict__ dinv,
                                                    float* __restrict__ st2, int n16) {
    __shared__ float sW[H1_ * H2_];   // 2 KB
    int tid = threadIdx.x;
    for (int i = tid; i < H1_ * H2_; i += 256) sW[i] = W2[i];
    __syncthreads();
    int idx = blockIdx.x * blockDim.x + tid;
    if (idx >= n16) return;
    int node = idx >> 4;
    int f    = idx & 15;
    if (f >= H2_) { st2[idx] = 0.0f; return; }   // zero padding for float4 gathers
    const float* hr = &h[(size_t)node * H1_];
    float acc = 0.0f;
#pragma unroll
    for (int k = 0; k < H1_; ++k) acc = fmaf(hr[k], sW[k * H2_ + f], acc);
    st2[idx] = acc * dinv[node];
}

// ====== aggregate layer 2: float4 gathers (4 threads/dst, g=3 idle) ======
// Writes z split: z0[N][8] (32B rows) + z1[N][2] (8B rows).

__global__ __launch_bounds__(256) void csr_aggregate2(const float* __restrict__ st,
                                                      const int* __restrict__ rowptr,
                                                      const int* __restrict__ ecol,
                                                      const float* __restrict__ dinv,
                                                      const float* __restrict__ b,
                                                      float* __restrict__ z0,
                                                      float* __restrict__ z1, int N) {
    int idx = blockIdx.x * blockDim.x + threadIdx.x;
    if (idx >= N * 4) return;
    int d = idx >> 2;
    int g = idx & 3;
    if (g == 3) return;                    // features 12..15: all zero, no output
    const float* row = st + g * 4;
    float4 acc = *(const float4*)(row + (size_t)d * ST2S);   // self-loop term
    int j = rowptr[d], end = rowptr[d + 1];
    for (; j + 3 < end; j += 4) {
        int s0 = ecol[j], s1 = ecol[j + 1], s2 = ecol[j + 2], s3 = ecol[j + 3];
        float4 a0 = *(const float4*)(row + (size_t)s0 * ST2S);
        float4 a1 = *(const float4*)(row + (size_t)s1 * ST2S);
        float4 a2 = *(const float4*)(row + (size_t)s2 * ST2S);
        float4 a3 = *(const float4*)(row + (size_t)s3 * ST2S);
        acc.x += (a0.x + a1.x) + (a2.x + a3.x);
        acc.y += (a0.y + a1.y) + (a2.y + a3.y);
        acc.z += (a0.z + a1.z) + (a2.z + a3.z);
        acc.w += (a0.w + a1.w) + (a2.w + a3.w);
    }
    for (; j < end; ++j) {
        float4 a = *(const float4*)(row + (size_t)ecol[j] * ST2S);
        acc.x += a.x; acc.y += a.y; acc.z += a.z; acc.w += a.w;
    }
    float vd = dinv[d];
    if (g < 2) {
        float4 r;
        r.x = fmaf(vd, acc.x, b[4 * g + 0]);
        r.y = fmaf(vd, acc.y, b[4 * g + 1]);
        r.z = fmaf(vd, acc.z, b[4 * g + 2]);
        r.w = fmaf(vd, acc.w, b[4 * g + 3]);
        *(float4*)(z0 + (size_t)d * 8 + 4 * g) = r;
    } else {                                // g==2: features 8,9 -> z1
        float2 r;
        r.x = fmaf(vd, acc.x, b[8]);
        r.y = fmaf(vd, acc.y, b[9]);
        *(float2*)(z1 + (size_t)d * 2) = r;
    }
}

// ================= decode: split-z gathers, 2 distinct lines per edge =======

__global__ __launch_bounds__(256) void decode_kernel(const float* __restrict__ z0,
                                                     const float* __restrict__ z1,
                                                     const int* __restrict__ pos,
                                                     const int* __restrict__ neg,
                                                     float* __restrict__ logits, int EP) {
    int i = blockIdx.x * blockDim.x + threadIdx.x;
    if (i >= 2 * EP) return;
    int a, b;
    if (i < EP) {
        a = __builtin_nontemporal_load(&pos[i]);
        b = __builtin_nontemporal_load(&pos[EP + i]);
    } else {
        int j = i - EP;
        a = __builtin_nontemporal_load(&neg[j]);
        b = __builtin_nontemporal_load(&neg[EP + j]);
    }
    const float4* za = (const float4*)(z0 + (size_t)a * 8);
    const float4* zb = (const float4*)(z0 + (size_t)b * 8);
    float4 a0 = za[0];
    float4 a1 = za[1];
    float4 b0 = zb[0];
    float4 b1 = zb[1];
    float2 a2 = *(const float2*)(z1 + (size_t)a * 2);
    float2 b2 = *(const float2*)(z1 + (size_t)b * 2);
    float acc = a0.x * b0.x;
    acc = fmaf(a0.y, b0.y, acc);
    acc = fmaf(a0.z, b0.z, acc);
    acc = fmaf(a0.w, b0.w, acc);
    acc = fmaf(a1.x, b1.x, acc);
    acc = fmaf(a1.y, b1.y, acc);
    acc = fmaf(a1.z, b1.z, acc);
    acc = fmaf(a1.w, b1.w, acc);
    acc = fmaf(a2.x, b2.x, acc);
    acc = fmaf(a2.y, b2.y, acc);
    __builtin_nontemporal_store(acc, &logits[i]);
}

// ================= launch =================

extern "C" void kernel_launch(void* const* d_in, const int* in_sizes, int n_in,
                              void* d_out, int out_size, void* d_ws, size_t ws_size,
                              hipStream_t stream) {
    const float* x   = (const float*)d_in[0];
    const float* W1  = (const float*)d_in[1];
    const float* b1  = (const float*)d_in[2];
    const float* W2  = (const float*)d_in[3];
    const float* b2  = (const float*)d_in[4];
    const int* train = (const int*)d_in[5];
    const int* pos   = (const int*)d_in[6];
    const int* neg   = (const int*)d_in[7];

    const int N  = in_sizes[0] / FIN;       // 100000
    const int E  = in_sizes[5] / 2;         // 3200000
    const int EP = in_sizes[6] / 2;         // 1600000

    const int* tsrc = train;
    const int* tdst = train + E;

    // ---- workspace layout (~34 MB peak) ----
    size_t off = 0;
    int* rowptr   = (int*)d_ws;              off += (size_t)N + 1;
    int* bcnt     = (int*)d_ws + off;        off += NB_MAX;
    int* sbcnt    = (int*)d_ws + off;        off += NSB_MAX;
    int* bbase    = (int*)d_ws + off;        off += NB_MAX + 1;
    int* bcursor  = (int*)d_ws + off;        off += NB_MAX;
    float* dinv   = (float*)d_ws + off;      off += N;
    off = (off + 15) & ~(size_t)15;          // 64B-align regA
    float* regA   = (float*)d_ws + off;      off += (size_t)32 * N;
    float* regB   = (float*)d_ws + off;
    int* pairbuf2 = (int*)regA;                      // E ints, dead after fill
    unsigned short* st1p = (unsigned short*)regA;    // 64N ushorts = 128N bytes
    float* st2    = regA;                            // 16N floats, overlays st1p after agg1
    float* z0     = regA + (size_t)16 * N;           // 8N floats (32B rows)
    float* z1     = regA + (size_t)24 * N;           // 2N floats (8B rows)
    int* pairbuf1 = (int*)regB;                      // 49*SB_CAP ints, dead after fine
    float* out1   = regB;                            // h after relu, 50N floats
    int* ecol     = (int*)d_out;                     // E ints; dead before decode
    float* logits = (float*)d_out;

    const int NB2 = (N + BKT_W - 1) >> BKT_SHIFT;   // 782 <= NB_MAX
    const int NSB = (N + SB_W - 1) >> SB_SHIFT;     // 49 <= NSB_MAX
    const int P1B = (E + P1_CHUNK - 1) / P1_CHUNK;  // 391
    const int P1FB = (SB_CAP + P1F_CHUNK - 1) / P1F_CHUNK;   // 20

    // ---- CSR build (fused count+partition; fill is src-chunk-sorted) ----
    hipMemsetAsync(bcnt, 0, (NB_MAX + NSB_MAX) * sizeof(int), stream);  // bcnt + sbcnt
    partition_sb<<<P1B, 256, 0, stream>>>(tsrc, tdst, sbcnt, bcnt, pairbuf1, E, NSB);
    bucket_scan<<<1, 256, 0, stream>>>(bcnt, bbase, bcursor, NB2, E);
    partition_fine<<<dim3(P1FB, NSB), 256, 0, stream>>>(pairbuf1, sbcnt, bcursor, pairbuf2);
    bucket_fill_scan<<<NB2, 256, 0, stream>>>(pairbuf2, bbase, rowptr, dinv, ecol, N, E);

    // ---- layer 1 ----
    gemm1_kernel<<<(N + G1_NODES - 1) / G1_NODES, 256, 0, stream>>>(x, W1, dinv, st1p, N);
    csr_aggregate1<<<(N * F2 + 255) / 256, 256, 0, stream>>>(
        st1p, rowptr, ecol, dinv, b1, out1, N);

    // ---- layer 2 ----
    gemm2_kernel<<<(N * 16 + 255) / 256, 256, 0, stream>>>(out1, W2, dinv, st2, N * 16);
    csr_aggregate2<<<(N * 4 + 255) / 256, 256, 0, stream>>>(
        st2, rowptr, ecol, dinv, b2, z0, z1, N);

    // ---- decode ----
    decode_kernel<<<(2 * EP + 255) / 256, 256, 0, stream>>>(z0, z1, pos, neg, logits, EP);
}